// Round 1
// baseline (124.534 us; speedup 1.0000x reference)
//
#include <hip/hip_runtime.h>
#include <hip/hip_cooperative_groups.h>

namespace cg = cooperative_groups;

// CenterLoss: scalar = 0.003 * ( sum_b clamp(||e_b - c_{l_b}||^2, 1e-12, 1e12)
//                                + B*(C-1)*1e-12 ) / B
// B=4096, D=512, C=10000, fp32; labels int32 (JAX default x64-disabled).
//
// Single cooperative dispatch: phase 1 computes per-row distances and one
// partial per block; grid.sync(); block 0 reduces partials and writes out.
// Rationale (rocprof): the two-kernel version's cost was launch overhead +
// a single-block second kernel, not bandwidth (~16 MB compulsory ~ 2.6 us).

#define LAMBDA_C  0.003f
#define CLAMP_MIN 1e-12f
#define CLAMP_MAX 1e12f

static constexpr int B = 4096;
static constexpr int D = 512;
static constexpr int C = 10000;

static constexpr int THREADS        = 256;               // 4 waves/block
static constexpr int BLOCKS         = 512;               // 2 blocks/CU -> trivially co-resident
static constexpr int WAVES_PER_BLK  = THREADS / 64;      // 4
static constexpr int TOTAL_WAVES    = BLOCKS * WAVES_PER_BLK;  // 2048
static constexpr int ROWS_PER_WAVE  = B / TOTAL_WAVES;   // 2

__global__ __launch_bounds__(THREADS) void center_loss_fused(
    const float* __restrict__ emb,
    const int*   __restrict__ labels,
    const float* __restrict__ centers,
    float*       __restrict__ out,
    float*       __restrict__ partials)   // BLOCKS floats in d_ws
{
    const int wid  = threadIdx.x >> 6;           // wave in block: 0..3
    const int lane = threadIdx.x & 63;
    const int gw   = (blockIdx.x << 2) | wid;    // global wave id: 0..2047
    const int row0 = gw * ROWS_PER_WAVE;         // each wave owns rows row0, row0+1

    // Wave-uniform label loads -> scalar loads.
    const int lab0 = labels[row0];
    const int lab1 = labels[row0 + 1];

    const float4* e0 = (const float4*)(emb     + (size_t)row0       * D);
    const float4* e1 = (const float4*)(emb     + (size_t)(row0 + 1) * D);
    const float4* c0 = (const float4*)(centers + (size_t)lab0       * D);
    const float4* c1 = (const float4*)(centers + (size_t)lab1       * D);

    // D=512 -> 128 float4/row; 64 lanes x 2 float4 per row. Both rows'
    // 8 independent float4 loads issue before any dependent math (MLP).
    float s0 = 0.0f, s1 = 0.0f;
#pragma unroll
    for (int k = 0; k < 2; ++k) {
        const int idx = lane + (k << 6);
        const float4 ea = e0[idx];
        const float4 ca = c0[idx];
        const float4 eb = e1[idx];
        const float4 cb = c1[idx];
        {
            const float dx = ea.x - ca.x, dy = ea.y - ca.y;
            const float dz = ea.z - ca.z, dw = ea.w - ca.w;
            s0 += dx * dx + dy * dy + dz * dz + dw * dw;
        }
        {
            const float dx = eb.x - cb.x, dy = eb.y - cb.y;
            const float dz = eb.z - cb.z, dw = eb.w - cb.w;
            s1 += dx * dx + dy * dy + dz * dz + dw * dw;
        }
    }

    // Dual 64-lane wave reduction (independent shuffle chains interleave).
#pragma unroll
    for (int off = 32; off > 0; off >>= 1) {
        s0 += __shfl_down(s0, off, 64);
        s1 += __shfl_down(s1, off, 64);
    }

    // Per-row clamp happens BEFORE the batch sum (matches reference).
    __shared__ float wsum[WAVES_PER_BLK];
    if (lane == 0) {
        wsum[wid] = fminf(fmaxf(s0, CLAMP_MIN), CLAMP_MAX)
                  + fminf(fmaxf(s1, CLAMP_MIN), CLAMP_MAX);
    }
    __syncthreads();

    if (threadIdx.x == 0) {
        partials[blockIdx.x] = wsum[0] + wsum[1] + wsum[2] + wsum[3];
    }

    // Grid-wide barrier (includes device-scope release/acquire fencing).
    cg::this_grid().sync();

    if (blockIdx.x == 0) {
        // 512 partials, 256 threads -> 2 each.
        float s = partials[threadIdx.x] + partials[threadIdx.x + THREADS];
#pragma unroll
        for (int off = 32; off > 0; off >>= 1)
            s += __shfl_down(s, off, 64);

        __shared__ float w2[WAVES_PER_BLK];
        if (lane == 0) w2[wid] = s;
        __syncthreads();

        if (threadIdx.x == 0) {
            const float total = w2[0] + w2[1] + w2[2] + w2[3];
            const float masked_floor = (float)B * (float)(C - 1) * CLAMP_MIN;
            out[0] = LAMBDA_C * ((total + masked_floor) / (float)B);
        }
    }
}

extern "C" void kernel_launch(void* const* d_in, const int* in_sizes, int n_in,
                              void* d_out, int out_size, void* d_ws, size_t ws_size,
                              hipStream_t stream)
{
    const float* emb      = (const float*)d_in[0];   // [B, D] fp32
    const int*   labels   = (const int*)  d_in[1];   // [B] int32
    const float* centers  = (const float*)d_in[2];   // [C, D] fp32
    float*       out      = (float*)d_out;           // [1] fp32
    float*       partials = (float*)d_ws;            // BLOCKS floats of scratch

    void* args[] = { (void*)&emb, (void*)&labels, (void*)&centers,
                     (void*)&out, (void*)&partials };
    hipLaunchCooperativeKernel((void*)center_loss_fused,
                               dim3(BLOCKS), dim3(THREADS),
                               args, 0, stream);
}

// Round 2
// 77.525 us; speedup vs baseline: 1.6064x; 1.6064x over previous
//
#include <hip/hip_runtime.h>

// CenterLoss: scalar = 0.003 * ( sum_b clamp(||e_b - c_{l_b}||^2, 1e-12, 1e12)
//                                + B*(C-1)*1e-12 ) / B
// B=4096, D=512, C=10000, fp32; labels int32.
//
// SINGLE regular kernel (graph-capturable; cooperative launch measured +51us
// in R1 -- it bypasses the cheap graph-replay path). Cross-block finish via a
// release/acquire handshake in workspace:
//   - each block stores {MAGIC,partial} packed in one u64 slot (agent scope)
//   - block 0 polls the 512 slots and writes the final scalar
// No zero-init needed: harness re-poisons the workspace each iteration, so
// slots start != MAGIC. If the graph is replayed multiple times per poison,
// stale slots carry values from an identical run -> result unchanged.
// Deadlock-safe: 512 blocks x 256 threads, tiny VGPR/LDS -> all co-resident
// on 256 CUs (>= 2 blocks/CU capacity), so writers always make progress.

#define LAMBDA_C  0.003f
#define CLAMP_MIN 1e-12f
#define CLAMP_MAX 1e12f

static constexpr int B = 4096;
static constexpr int D = 512;
static constexpr int C = 10000;

static constexpr int      THREADS       = 256;   // 4 waves/block
static constexpr int      BLOCKS        = 512;   // 2 blocks/CU
static constexpr int      WAVES_PER_BLK = THREADS / 64;
static constexpr int      ROWS_PER_WAVE = B / (BLOCKS * WAVES_PER_BLK);  // 2
static constexpr unsigned MAGIC         = 0x7F3A9C51u;  // non-repeating bytes:
                                                        // won't collide with a
                                                        // byte-pattern poison

__global__ __launch_bounds__(THREADS) void center_loss_onepass(
    const float* __restrict__ emb,
    const int*   __restrict__ labels,
    const float* __restrict__ centers,
    float*       __restrict__ out,
    unsigned long long* __restrict__ slots)   // BLOCKS u64 slots in d_ws
{
    const int wid  = threadIdx.x >> 6;           // 0..3
    const int lane = threadIdx.x & 63;
    const int gw   = (blockIdx.x << 2) | wid;    // 0..2047
    const int row0 = gw * ROWS_PER_WAVE;

    const int lab0 = labels[row0];
    const int lab1 = labels[row0 + 1];

    const float4* e0 = (const float4*)(emb     + (size_t)row0       * D);
    const float4* e1 = (const float4*)(emb     + (size_t)(row0 + 1) * D);
    const float4* c0 = (const float4*)(centers + (size_t)lab0       * D);
    const float4* c1 = (const float4*)(centers + (size_t)lab1       * D);

    // D=512 -> 128 float4/row; 64 lanes x 2 float4 per row. All 8 independent
    // float4 loads issue before dependent math (memory-level parallelism).
    float s0 = 0.0f, s1 = 0.0f;
#pragma unroll
    for (int k = 0; k < 2; ++k) {
        const int idx = lane + (k << 6);
        const float4 ea = e0[idx];
        const float4 ca = c0[idx];
        const float4 eb = e1[idx];
        const float4 cb = c1[idx];
        {
            const float dx = ea.x - ca.x, dy = ea.y - ca.y;
            const float dz = ea.z - ca.z, dw = ea.w - ca.w;
            s0 += dx * dx + dy * dy + dz * dz + dw * dw;
        }
        {
            const float dx = eb.x - cb.x, dy = eb.y - cb.y;
            const float dz = eb.z - cb.z, dw = eb.w - cb.w;
            s1 += dx * dx + dy * dy + dz * dz + dw * dw;
        }
    }

    // Dual 64-lane wave reduction (independent shuffle chains interleave).
#pragma unroll
    for (int off = 32; off > 0; off >>= 1) {
        s0 += __shfl_down(s0, off, 64);
        s1 += __shfl_down(s1, off, 64);
    }

    // Per-row clamp BEFORE the batch sum (matches reference).
    __shared__ float wsum[WAVES_PER_BLK];
    if (lane == 0) {
        wsum[wid] = fminf(fmaxf(s0, CLAMP_MIN), CLAMP_MAX)
                  + fminf(fmaxf(s1, CLAMP_MIN), CLAMP_MAX);
    }
    __syncthreads();

    if (threadIdx.x == 0) {
        const float bsum = wsum[0] + wsum[1] + wsum[2] + wsum[3];
        const unsigned long long packed =
            ((unsigned long long)MAGIC << 32) |
            (unsigned long long)__float_as_uint(bsum);
        __hip_atomic_store(&slots[blockIdx.x], packed,
                           __ATOMIC_RELEASE, __HIP_MEMORY_SCOPE_AGENT);
    }

    if (blockIdx.x != 0) return;   // only block 0 finishes

    // ---- finisher: 256 threads poll 2 slots each (512 total) ----
    float s = 0.0f;
#pragma unroll
    for (int j = 0; j < BLOCKS / THREADS; ++j) {
        const int i = threadIdx.x + j * THREADS;
        unsigned long long v;
        do {
            v = __hip_atomic_load(&slots[i],
                                  __ATOMIC_ACQUIRE, __HIP_MEMORY_SCOPE_AGENT);
        } while ((unsigned)(v >> 32) != MAGIC);
        s += __uint_as_float((unsigned)(v & 0xFFFFFFFFull));
    }

#pragma unroll
    for (int off = 32; off > 0; off >>= 1)
        s += __shfl_down(s, off, 64);

    __shared__ float w2[WAVES_PER_BLK];   // separate array: no race with wsum
    if (lane == 0) w2[wid] = s;
    __syncthreads();

    if (threadIdx.x == 0) {
        const float total = w2[0] + w2[1] + w2[2] + w2[3];
        const float masked_floor = (float)B * (float)(C - 1) * CLAMP_MIN;
        out[0] = LAMBDA_C * ((total + masked_floor) / (float)B);
    }
}

extern "C" void kernel_launch(void* const* d_in, const int* in_sizes, int n_in,
                              void* d_out, int out_size, void* d_ws, size_t ws_size,
                              hipStream_t stream)
{
    const float* emb     = (const float*)d_in[0];   // [B, D] fp32
    const int*   labels  = (const int*)  d_in[1];   // [B] int32
    const float* centers = (const float*)d_in[2];   // [C, D] fp32
    float*       out     = (float*)d_out;           // [1] fp32
    unsigned long long* slots = (unsigned long long*)d_ws;  // BLOCKS u64

    center_loss_onepass<<<BLOCKS, THREADS, 0, stream>>>(
        emb, labels, centers, out, slots);
}

// Round 3
// 73.482 us; speedup vs baseline: 1.6948x; 1.0550x over previous
//
#include <hip/hip_runtime.h>

// CenterLoss: scalar = 0.003 * ( sum_b clamp(||e_b - c_{l_b}||^2, 1e-12, 1e12)
//                                + B*(C-1)*1e-12 ) / B
// B=4096, D=512, C=10000, fp32; labels int32.
//
// Structure: TWO plain graph nodes (best measured: 73.7 us in R0).
//  - R1 (cooperative launch, grid.sync): 124.5 us -- coop bypasses the cheap
//    graph-replay path. Rejected.
//  - R2 (single kernel, release/acquire slot handshake): 77.5 us -- the
//    agent-scope store+poll round trip costs >= a graph-node gap. Rejected.
// Envelope per timed iter: ~44 us harness poison-fill (256 MiB @ ~76% peak,
// fixed) + ~25 us reset/replay overhead (fixed) + ~5 us ours (16 MB read,
// latency-bound). Changes below are micro-trims of kernel 2's load chain:
// kernel 1 emits 1024 block partials (not 4096 row values), kernel 2 reads
// exactly one float4 per thread.

#define LAMBDA_C  0.003f
#define CLAMP_MIN 1e-12f
#define CLAMP_MAX 1e12f

static constexpr int B = 4096;
static constexpr int D = 512;
static constexpr int C = 10000;

static constexpr int THREADS       = 256;          // 4 waves/block
static constexpr int BLOCKS        = B / 4;        // 1024: one row per wave
static constexpr int WAVES_PER_BLK = THREADS / 64; // 4

// One 64-lane wave per row. Lane i reads float4 at [lane + k*64]:
// consecutive lanes -> consecutive 16B, fully coalesced (1 KiB/wave/instr).
__global__ __launch_bounds__(THREADS) void row_dist_kernel(
    const float* __restrict__ emb,
    const int*   __restrict__ labels,
    const float* __restrict__ centers,
    float*       __restrict__ partials)   // [BLOCKS] floats in d_ws
{
    const int wid  = threadIdx.x >> 6;          // 0..3
    const int lane = threadIdx.x & 63;
    const int row  = (blockIdx.x << 2) + wid;   // 0..4095

    const int label = labels[row];              // wave-uniform -> scalar load
    const float4* e4 = (const float4*)(emb     + (size_t)row   * D);
    const float4* c4 = (const float4*)(centers + (size_t)label * D);

    // D=512 -> 128 float4/row; 64 lanes x 2 float4 each. Issue all 4
    // independent loads before any dependent math.
    const float4 ea = e4[lane];
    const float4 ca = c4[lane];
    const float4 eb = e4[lane + 64];
    const float4 cb = c4[lane + 64];

    float s;
    {
        const float dx = ea.x - ca.x, dy = ea.y - ca.y;
        const float dz = ea.z - ca.z, dw = ea.w - ca.w;
        s = dx * dx + dy * dy + dz * dz + dw * dw;
    }
    {
        const float dx = eb.x - cb.x, dy = eb.y - cb.y;
        const float dz = eb.z - cb.z, dw = eb.w - cb.w;
        s += dx * dx + dy * dy + dz * dz + dw * dw;
    }

    // 64-lane wave reduction.
#pragma unroll
    for (int off = 32; off > 0; off >>= 1)
        s += __shfl_down(s, off, 64);

    // Per-row clamp BEFORE the batch sum (matches reference).
    __shared__ float wsum[WAVES_PER_BLK];
    if (lane == 0)
        wsum[wid] = fminf(fmaxf(s, CLAMP_MIN), CLAMP_MAX);
    __syncthreads();

    if (threadIdx.x == 0)
        partials[blockIdx.x] = wsum[0] + wsum[1] + wsum[2] + wsum[3];
}

// Single-block reduction of 1024 block partials -> scalar.
__global__ __launch_bounds__(THREADS) void reduce_kernel(
    const float* __restrict__ partials,
    float*       __restrict__ out)
{
    const int tid  = threadIdx.x;
    const int wid  = tid >> 6;
    const int lane = tid & 63;

    // 1024 floats = 256 float4: exactly one per thread.
    const float4 v = ((const float4*)partials)[tid];
    float s = v.x + v.y + v.z + v.w;

#pragma unroll
    for (int off = 32; off > 0; off >>= 1)
        s += __shfl_down(s, off, 64);

    __shared__ float wsum[WAVES_PER_BLK];
    if (lane == 0) wsum[wid] = s;
    __syncthreads();

    if (tid == 0) {
        const float total = wsum[0] + wsum[1] + wsum[2] + wsum[3];
        const float masked_floor = (float)B * (float)(C - 1) * CLAMP_MIN;
        out[0] = LAMBDA_C * ((total + masked_floor) / (float)B);
    }
}

extern "C" void kernel_launch(void* const* d_in, const int* in_sizes, int n_in,
                              void* d_out, int out_size, void* d_ws, size_t ws_size,
                              hipStream_t stream)
{
    const float* emb      = (const float*)d_in[0];   // [B, D] fp32
    const int*   labels   = (const int*)  d_in[1];   // [B] int32
    const float* centers  = (const float*)d_in[2];   // [C, D] fp32
    float*       out      = (float*)d_out;           // [1] fp32
    float*       partials = (float*)d_ws;            // BLOCKS floats of scratch

    row_dist_kernel<<<BLOCKS, THREADS, 0, stream>>>(emb, labels, centers, partials);
    reduce_kernel<<<1, THREADS, 0, stream>>>(partials, out);
}